// Round 6
// baseline (431.713 us; speedup 1.0000x reference)
//
#include <hip/hip_runtime.h>
#include <hip/hip_bf16.h>
#include <stdint.h>

#define S_LEN 2048
#define DM 1024
#define NH 16
#define HD 64

typedef __bf16 bf16x8 __attribute__((ext_vector_type(8)));
typedef float f32x4 __attribute__((ext_vector_type(4)));
typedef unsigned short u16x4 __attribute__((ext_vector_type(4)));

#if __has_builtin(__builtin_amdgcn_exp2f)
#define EXP2F(x) __builtin_amdgcn_exp2f(x)
#else
#define EXP2F(x) exp2f(x)
#endif

__device__ __forceinline__ unsigned short f2bf(float f){
  union { float f; uint32_t u; } v; v.f = f;
  uint32_t r = v.u + 0x7fffu + ((v.u >> 16) & 1u);
  return (unsigned short)(r >> 16);
}

__device__ __forceinline__ void load_lds16(const void* g, void* l){
  __builtin_amdgcn_global_load_lds((const __attribute__((address_space(1))) void*)g,
                                   (__attribute__((address_space(3))) void*)l, 16, 0, 0);
}

__device__ __forceinline__ f32x4 mfma16(bf16x8 a, bf16x8 b, f32x4 c){
  return __builtin_amdgcn_mfma_f32_16x16x32_bf16(a, b, c, 0, 0, 0);
}

// rows are 64 bf16 = 128B; swizzle byte_off ^= ((row&7)<<4) to break the 128B-stride bank conflict
__device__ __forceinline__ bf16x8 lds_swz_read(const unsigned short* base, int row, int cb){
  int addr = (row << 7) + (cb ^ ((row & 7) << 4));
  return *reinterpret_cast<const bf16x8*>(reinterpret_cast<const char*>(base) + addr);
}

// ---------------- prep: f32 -> bf16 for x and the 4 weight matrices ----------------
__global__ void prep_kernel(const float* __restrict__ x,
                            const float* __restrict__ wq, const float* __restrict__ wk,
                            const float* __restrict__ wv, const float* __restrict__ wo,
                            unsigned short* __restrict__ ws_base){
  long idx = ((long)blockIdx.x * 256 + threadIdx.x) * 4;
  const float* s; unsigned short* d; long off;
  if (idx < (1L << 22)) { s = x; d = ws_base; off = idx; }
  else {
    long r = idx - (1L << 22);
    int wsel = (int)(r >> 20);
    off = r & ((1L << 20) - 1);
    s = wsel == 0 ? wq : wsel == 1 ? wk : wsel == 2 ? wv : wo;
    d = ws_base + (1L << 22) + ((long)wsel << 20);
  }
  float4 f = *reinterpret_cast<const float4*>(s + off);
  u16x4 o;
  o[0] = f2bf(f.x); o[1] = f2bf(f.y); o[2] = f2bf(f.z); o[3] = f2bf(f.w);
  *reinterpret_cast<u16x4*>(d + off) = o;
}

// ---------------- GEMM: C = A[M,1024] * B[N,1024]^T + bias ----------------
// MODE 0: fused QKV (A = x_bf16). grid.x = 24: nb>>3 selects Q/K/V. Q,K stored [B,H,S,64]; V stored [B,H,64,S].
// MODE 1: output projection (A = ctx_bf16), f32 flat output.
template<int MODE>
__global__ __launch_bounds__(256, 2)
void gemm_bt_kernel(const unsigned short* __restrict__ A,
                    const unsigned short* __restrict__ B0,
                    const unsigned short* __restrict__ B1,
                    const unsigned short* __restrict__ B2,
                    const float* __restrict__ bias0,
                    const float* __restrict__ bias1,
                    const float* __restrict__ bias2,
                    unsigned short* __restrict__ q_out,
                    unsigned short* __restrict__ k_out,
                    unsigned short* __restrict__ vt_out,
                    float* __restrict__ f_out)
{
  __shared__ unsigned short As[128 * 64];
  __shared__ unsigned short Bs[128 * 64];
  const int tid = threadIdx.x;
  const int lane = tid & 63;
  const int w = tid >> 6;
  const int wr = w >> 1, wc = w & 1;
  const int mBase = blockIdx.y * 128;
  int nb = blockIdx.x;
  const unsigned short* Bmat; const float* bias; int mat;
  if constexpr (MODE == 0) {
    mat = nb >> 3;
    nb &= 7;
    Bmat = mat == 0 ? B0 : (mat == 1 ? B1 : B2);
    bias = mat == 0 ? bias0 : (mat == 1 ? bias1 : bias2);
  } else { mat = 0; Bmat = B0; bias = bias0; }
  const int nBase = nb * 128;

  f32x4 acc[4][4] = {};
  const int srow = lane >> 3;                 // row within 8-row chunk
  const int ksrc = ((lane & 7) ^ srow) * 8;   // pre-swizzled source k-offset (elements)
  const unsigned short* ArowBase = A    + (size_t)(mBase + w * 32 + srow) * DM + ksrc;
  const unsigned short* BrowBase = Bmat + (size_t)(nBase + w * 32 + srow) * DM + ksrc;

  for (int kt = 0; kt < 16; ++kt) {
    #pragma unroll
    for (int i = 0; i < 4; ++i) {
      load_lds16(ArowBase + (size_t)(i * 8) * DM + kt * 64, &As[(w * 4 + i) * 512]);
      load_lds16(BrowBase + (size_t)(i * 8) * DM + kt * 64, &Bs[(w * 4 + i) * 512]);
    }
    __syncthreads();
    #pragma unroll
    for (int kk = 0; kk < 2; ++kk) {
      bf16x8 af[4], bfr[4];
      const int cb = kk * 64 + ((lane >> 4) << 4);
      #pragma unroll
      for (int m = 0; m < 4; ++m)
        af[m] = lds_swz_read(As, wr * 64 + m * 16 + (lane & 15), cb);
      #pragma unroll
      for (int n = 0; n < 4; ++n)
        bfr[n] = lds_swz_read(Bs, wc * 64 + n * 16 + (lane & 15), cb);
      #pragma unroll
      for (int m = 0; m < 4; ++m)
        #pragma unroll
        for (int n = 0; n < 4; ++n)
          acc[m][n] = mfma16(af[m], bfr[n], acc[m][n]);
    }
    __syncthreads();
  }

  // epilogue: bias + store
  #pragma unroll
  for (int m = 0; m < 4; ++m) {
    #pragma unroll
    for (int n = 0; n < 4; ++n) {
      const int col = nBase + wc * 64 + n * 16 + (lane & 15);
      const float bv = bias[col];
      const int row0 = mBase + wr * 64 + m * 16 + ((lane >> 4) << 2);
      if constexpr (MODE == 1) {
        #pragma unroll
        for (int j = 0; j < 4; ++j)
          f_out[(size_t)(row0 + j) * DM + col] = acc[m][n][j] + bv;
      } else {
        const int h = col >> 6, d = col & 63;
        if (mat < 2) {
          unsigned short* dst = (mat == 0) ? q_out : k_out;
          #pragma unroll
          for (int j = 0; j < 4; ++j) {
            const int row = row0 + j;
            const int b = row >> 11, s = row & 2047;
            dst[(((size_t)b * NH + h) * S_LEN + s) * HD + d] = f2bf(acc[m][n][j] + bv);
          }
        } else {
          const int b = row0 >> 11, s = row0 & 2047;
          u16x4 pk;
          #pragma unroll
          for (int j = 0; j < 4; ++j) pk[j] = f2bf(acc[m][n][j] + bv);
          *reinterpret_cast<u16x4*>(&vt_out[(((size_t)b * NH + h) * HD + d) * S_LEN + s]) = pk;
        }
      }
    }
  }
}

// ---------------- flash attention: BARRIER-FREE register-fragment pipeline ----------------
// Key insight vs round 5: hipcc drains vmcnt(0) at every __syncthreads, killing all
// prefetch. So remove barriers entirely: K and V^T fragments are loaded DIRECTLY from
// global into MFMA A-operand registers (K/V = 16 MB total, L2/L3-resident; redundant
// per-wave reads cost only L2 BW). P stays in per-wave LDS (wave-local lgkm only).
// Per-iteration FIFO: combine bias(t) -> issue bias(t+1) -> QK(K t) -> issue K(t+1)
// -> softmax -> PV(V t) -> issue V(t+1). Queue never drains; each consumer has ~one
// full iteration of latency cover. All state in named f32x4/bf16x8 (no arrays).

#define LOAD_RAW(kvB) do {                                                    \
    rb0 = *reinterpret_cast<const f32x4*>(bp + (kvB) + g * 4);                \
    rm0 = *reinterpret_cast<const f32x4*>(mp + (kvB) + g * 4);                \
    rb1 = *reinterpret_cast<const f32x4*>(bp + (kvB) + 16 + g * 4);           \
    rm1 = *reinterpret_cast<const f32x4*>(mp + (kvB) + 16 + g * 4);           \
    rb2 = *reinterpret_cast<const f32x4*>(bp + (kvB) + 32 + g * 4);           \
    rm2 = *reinterpret_cast<const f32x4*>(mp + (kvB) + 32 + g * 4);           \
    rb3 = *reinterpret_cast<const f32x4*>(bp + (kvB) + 48 + g * 4);           \
    rm3 = *reinterpret_cast<const f32x4*>(mp + (kvB) + 48 + g * 4);           \
  } while (0)

#define COMBINE do {                                                          \
    bm0 = (rb0 + rm0) * L2E; bm1 = (rb1 + rm1) * L2E;                         \
    bm2 = (rb2 + rm2) * L2E; bm3 = (rb3 + rm3) * L2E;                         \
  } while (0)

// K fragment: lane(q,g) reads K[(kvB + n*16 + q)*64 + g*8 (+32)]
#define LOAD_K(kvB) do {                                                      \
    kf00 = *reinterpret_cast<const bf16x8*>(Kq + (size_t)(kvB) * HD);         \
    kf01 = *reinterpret_cast<const bf16x8*>(Kq + (size_t)(kvB) * HD + 32);    \
    kf10 = *reinterpret_cast<const bf16x8*>(Kq + (size_t)(kvB) * HD + 1024);  \
    kf11 = *reinterpret_cast<const bf16x8*>(Kq + (size_t)(kvB) * HD + 1056);  \
    kf20 = *reinterpret_cast<const bf16x8*>(Kq + (size_t)(kvB) * HD + 2048);  \
    kf21 = *reinterpret_cast<const bf16x8*>(Kq + (size_t)(kvB) * HD + 2080);  \
    kf30 = *reinterpret_cast<const bf16x8*>(Kq + (size_t)(kvB) * HD + 3072);  \
    kf31 = *reinterpret_cast<const bf16x8*>(Kq + (size_t)(kvB) * HD + 3104);  \
  } while (0)

// V^T fragment: lane(q,g) reads Vt[(n*16 + q)*2048 + kvB + g*8 (+32)]
#define LOAD_V(kvB) do {                                                      \
    vf00 = *reinterpret_cast<const bf16x8*>(Vq0 + (kvB));                     \
    vf01 = *reinterpret_cast<const bf16x8*>(Vq0 + (kvB) + 32);                \
    vf10 = *reinterpret_cast<const bf16x8*>(Vq1 + (kvB));                     \
    vf11 = *reinterpret_cast<const bf16x8*>(Vq1 + (kvB) + 32);                \
    vf20 = *reinterpret_cast<const bf16x8*>(Vq2 + (kvB));                     \
    vf21 = *reinterpret_cast<const bf16x8*>(Vq2 + (kvB) + 32);                \
    vf30 = *reinterpret_cast<const bf16x8*>(Vq3 + (kvB));                     \
    vf31 = *reinterpret_cast<const bf16x8*>(Vq3 + (kvB) + 32);                \
  } while (0)

#define BIAS_COL(SCN, BMN) do {                                               \
    SCN[0] = SCN[0] * SC + BMN[0];                                            \
    SCN[1] = SCN[1] * SC + BMN[1];                                            \
    SCN[2] = SCN[2] * SC + BMN[2];                                            \
    SCN[3] = SCN[3] * SC + BMN[3];                                            \
    mt_ = fmaxf(mt_, fmaxf(fmaxf(SCN[0], SCN[1]), fmaxf(SCN[2], SCN[3])));    \
  } while (0)

#define EXP_COL(SCN) do {                                                     \
    SCN[0] = EXP2F(SCN[0] - mn_); SCN[1] = EXP2F(SCN[1] - mn_);               \
    SCN[2] = EXP2F(SCN[2] - mn_); SCN[3] = EXP2F(SCN[3] - mn_);               \
  } while (0)

#define PWR_COL(NN, SCN) do {                                                 \
    u16x4 pk_;                                                                \
    pk_[0] = f2bf(SCN[0]); pk_[1] = f2bf(SCN[1]);                             \
    pk_[2] = f2bf(SCN[2]); pk_[3] = f2bf(SCN[3]);                             \
    const int colb_ = ((NN) * 16 + 4 * g) * 2;                                \
    *reinterpret_cast<u16x4*>(                                                \
        reinterpret_cast<char*>(Pw_) + (q << 7) + (colb_ ^ ((q & 7) << 4))) = pk_; \
  } while (0)

__global__ __launch_bounds__(256) __attribute__((amdgpu_waves_per_eu(3, 4)))
void attn_kernel(const unsigned short* __restrict__ Q,
                 const unsigned short* __restrict__ Kmat,
                 const unsigned short* __restrict__ Vt,
                 const float* __restrict__ rel_bias,
                 const float* __restrict__ mask,
                 unsigned short* __restrict__ ctx)
{
  __shared__ unsigned short Ps[4][16 * 64];   // per-wave P buffer (wave-local, no barriers)

  // XCD-chunked bijective remap: 1024 = 8 XCDs x 128; b is fastest in logical id
  const int logical = (blockIdx.x & 7) * 128 + (blockIdx.x >> 3);
  const int b  = logical & 1;
  const int qt = (logical >> 1) & 31;
  const int h  = logical >> 6;

  const int lane = threadIdx.x & 63, w = threadIdx.x >> 6;
  const int q = lane & 15, g = lane >> 4;
  const size_t bh = (size_t)b * NH + h;
  const int qRow = qt * 64 + w * 16;
  const unsigned short* Qp = Q + (bh * S_LEN + qRow) * HD;
  bf16x8 qf0 = *reinterpret_cast<const bf16x8*>(Qp + (size_t)q * HD + g * 8);
  bf16x8 qf1 = *reinterpret_cast<const bf16x8*>(Qp + (size_t)q * HD + 32 + g * 8);

  // fragment base pointers
  const unsigned short* Kq  = Kmat + bh * (size_t)S_LEN * HD + (size_t)q * HD + g * 8;
  const unsigned short* Vb  = Vt + bh * (size_t)HD * S_LEN + g * 8;
  const unsigned short* Vq0 = Vb + (size_t)q * S_LEN;
  const unsigned short* Vq1 = Vb + (size_t)(16 + q) * S_LEN;
  const unsigned short* Vq2 = Vb + (size_t)(32 + q) * S_LEN;
  const unsigned short* Vq3 = Vb + (size_t)(48 + q) * S_LEN;
  const float* bp = rel_bias + (size_t)h * S_LEN * S_LEN + (size_t)(qRow + q) * S_LEN;
  const float* mp = mask + (size_t)(qRow + q) * S_LEN;

  float m_run = -3.0e38f, l_run = 0.f;
  f32x4 acc0_ = {}, acc1_ = {}, acc2_ = {}, acc3_ = {};
  f32x4 rb0, rb1, rb2, rb3, rm0, rm1, rm2, rm3;
  f32x4 bm0, bm1, bm2, bm3;
  bf16x8 kf00, kf01, kf10, kf11, kf20, kf21, kf30, kf31;
  bf16x8 vf00, vf01, vf10, vf11, vf20, vf21, vf30, vf31;

  const float SC  = 0.125f * 1.44269504089f;  // head scale * log2(e)
  const float L2E = 1.44269504089f;
  const int cbq = g << 4;
  unsigned short* Pw_ = Ps[w];

  // prologue: tile-0 bias/mask + K + V into the pipeline
  LOAD_RAW(0);
  LOAD_K(0);
  LOAD_V(0);

  for (int t = 0; t < 32; ++t) {
    const int nxt = (t + 1) * 64;
    COMBINE;                                   // waits raw(t) (oldest in FIFO)
    if (t < 31) LOAD_RAW(nxt);                 // issue bias/mask(t+1)

    // QK^T (transposed): sc_n[j] = scores^T[k = t*64 + n*16 + 4g + j][q]
    f32x4 sc0_, sc1_, sc2_, sc3_;
    { f32x4 z_ = {}; z_ = mfma16(kf00, qf0, z_); sc0_ = mfma16(kf01, qf1, z_); }
    { f32x4 z_ = {}; z_ = mfma16(kf10, qf0, z_); sc1_ = mfma16(kf11, qf1, z_); }
    { f32x4 z_ = {}; z_ = mfma16(kf20, qf0, z_); sc2_ = mfma16(kf21, qf1, z_); }
    { f32x4 z_ = {}; z_ = mfma16(kf30, qf0, z_); sc3_ = mfma16(kf31, qf1, z_); }
    if (t < 31) LOAD_K(nxt);                   // kf regs now free; issue K(t+1)

    // online softmax
    float mt_ = -3.0e38f;
    BIAS_COL(sc0_, bm0); BIAS_COL(sc1_, bm1);
    BIAS_COL(sc2_, bm2); BIAS_COL(sc3_, bm3);
    mt_ = fmaxf(mt_, __shfl_xor(mt_, 16));
    mt_ = fmaxf(mt_, __shfl_xor(mt_, 32));
    const float mn_ = fmaxf(m_run, mt_);
    const float corr_ = EXP2F(m_run - mn_);
    m_run = mn_;
    EXP_COL(sc0_); EXP_COL(sc1_); EXP_COL(sc2_); EXP_COL(sc3_);
    f32x4 ls4_ = sc0_ + sc1_ + sc2_ + sc3_;
    float ls_ = ls4_[0] + ls4_[1] + ls4_[2] + ls4_[3];
    ls_ += __shfl_xor(ls_, 16);
    ls_ += __shfl_xor(ls_, 32);
    l_run = l_run * corr_ + ls_;
    acc0_ *= corr_; acc1_ *= corr_; acc2_ *= corr_; acc3_ *= corr_;

    // P^T -> per-wave swizzled LDS -> B-fragment (wave-local: lgkm only)
    PWR_COL(0, sc0_); PWR_COL(1, sc1_); PWR_COL(2, sc2_); PWR_COL(3, sc3_);
    bf16x8 pf0_ = lds_swz_read(Pw_, q, cbq);
    bf16x8 pf1_ = lds_swz_read(Pw_, q, 64 + cbq);

    // ctx^T[d][q] += V^T * P^T
    acc0_ = mfma16(vf00, pf0_, acc0_); acc0_ = mfma16(vf01, pf1_, acc0_);
    acc1_ = mfma16(vf10, pf0_, acc1_); acc1_ = mfma16(vf11, pf1_, acc1_);
    acc2_ = mfma16(vf20, pf0_, acc2_); acc2_ = mfma16(vf21, pf1_, acc2_);
    acc3_ = mfma16(vf30, pf0_, acc3_); acc3_ = mfma16(vf31, pf1_, acc3_);
    if (t < 31) LOAD_V(nxt);                   // vf regs free; issue V(t+1)
  }

  // epilogue: normalize, redistribute through per-wave LDS, coalesced 16B stores
  const float inv = 1.0f / l_run;
  acc0_ *= inv; acc1_ *= inv; acc2_ *= inv; acc3_ *= inv;
  PWR_COL(0, acc0_); PWR_COL(1, acc1_); PWR_COL(2, acc2_); PWR_COL(3, acc3_);
  bf16x8 c0 = lds_swz_read(Pw_, q, g << 4);
  bf16x8 c1 = lds_swz_read(Pw_, q, 64 + (g << 4));
  unsigned short* cp = ctx + ((size_t)b * S_LEN + qRow + q) * DM + h * HD;
  *reinterpret_cast<bf16x8*>(cp + 8 * g) = c0;
  *reinterpret_cast<bf16x8*>(cp + 32 + 8 * g) = c1;
}

extern "C" void kernel_launch(void* const* d_in, const int* in_sizes, int n_in,
                              void* d_out, int out_size, void* d_ws, size_t ws_size,
                              hipStream_t stream) {
  (void)in_sizes; (void)n_in; (void)out_size; (void)ws_size;
  const float* x  = (const float*)d_in[0];
  const float* rb = (const float*)d_in[1];
  const float* mk = (const float*)d_in[2];
  const float* Wq = (const float*)d_in[3];
  const float* bq = (const float*)d_in[4];
  const float* Wk = (const float*)d_in[5];
  const float* bk = (const float*)d_in[6];
  const float* Wv = (const float*)d_in[7];
  const float* bv = (const float*)d_in[8];
  const float* Wo = (const float*)d_in[9];
  const float* bo = (const float*)d_in[10];
  float* out = (float*)d_out;

  unsigned short* ws  = (unsigned short*)d_ws;
  unsigned short* xb  = ws;                       // 4M elems
  unsigned short* wqb = ws + (1L << 22);          // 1M
  unsigned short* wkb = wqb + (1L << 20);
  unsigned short* wvb = wkb + (1L << 20);
  unsigned short* wob = wvb + (1L << 20);
  unsigned short* Qw  = wob + (1L << 20);         // 4M [B,H,S,64]
  unsigned short* Kw  = Qw + (1L << 22);          // 4M [B,H,S,64]
  unsigned short* Vtw = Kw + (1L << 22);          // 4M [B,H,64,S]
  unsigned short* ctx = Vtw + (1L << 22);         // 4M [B,S,DM]

  prep_kernel<<<8192, 256, 0, stream>>>(x, Wq, Wk, Wv, Wo, ws);
  gemm_bt_kernel<0><<<dim3(24, 32), 256, 0, stream>>>(
      xb, wqb, wkb, wvb, bq, bk, bv, Qw, Kw, Vtw, nullptr);
  attn_kernel<<<1024, 256, 0, stream>>>(Qw, Kw, Vtw, rb, mk, ctx);
  gemm_bt_kernel<1><<<dim3(8, 32), 256, 0, stream>>>(
      ctx, wob, nullptr, nullptr, bo, nullptr, nullptr, nullptr, nullptr, nullptr, out);
}

// Round 7
// 241.156 us; speedup vs baseline: 1.7902x; 1.7902x over previous
//
#include <hip/hip_runtime.h>
#include <hip/hip_bf16.h>
#include <stdint.h>

#define S_LEN 2048
#define DM 1024
#define NH 16
#define HD 64

typedef __bf16 bf16x8 __attribute__((ext_vector_type(8)));
typedef float f32x4 __attribute__((ext_vector_type(4)));
typedef unsigned short u16x4 __attribute__((ext_vector_type(4)));

#if __has_builtin(__builtin_amdgcn_exp2f)
#define EXP2F(x) __builtin_amdgcn_exp2f(x)
#else
#define EXP2F(x) exp2f(x)
#endif

__device__ __forceinline__ unsigned short f2bf(float f){
  union { float f; uint32_t u; } v; v.f = f;
  uint32_t r = v.u + 0x7fffu + ((v.u >> 16) & 1u);
  return (unsigned short)(r >> 16);
}

__device__ __forceinline__ void load_lds16(const void* g, void* l){
  __builtin_amdgcn_global_load_lds((const __attribute__((address_space(1))) void*)g,
                                   (__attribute__((address_space(3))) void*)l, 16, 0, 0);
}

__device__ __forceinline__ f32x4 mfma16(bf16x8 a, bf16x8 b, f32x4 c){
  return __builtin_amdgcn_mfma_f32_16x16x32_bf16(a, b, c, 0, 0, 0);
}

// rows are 64 bf16 = 128B; swizzle byte_off ^= ((row&7)<<4) to break the 128B-stride bank conflict
__device__ __forceinline__ bf16x8 lds_swz_read(const unsigned short* base, int row, int cb){
  int addr = (row << 7) + (cb ^ ((row & 7) << 4));
  return *reinterpret_cast<const bf16x8*>(reinterpret_cast<const char*>(base) + addr);
}

// ---------------- prep: f32 -> bf16 for x and the 4 weight matrices ----------------
__global__ void prep_kernel(const float* __restrict__ x,
                            const float* __restrict__ wq, const float* __restrict__ wk,
                            const float* __restrict__ wv, const float* __restrict__ wo,
                            unsigned short* __restrict__ ws_base){
  long idx = ((long)blockIdx.x * 256 + threadIdx.x) * 4;
  const float* s; unsigned short* d; long off;
  if (idx < (1L << 22)) { s = x; d = ws_base; off = idx; }
  else {
    long r = idx - (1L << 22);
    int wsel = (int)(r >> 20);
    off = r & ((1L << 20) - 1);
    s = wsel == 0 ? wq : wsel == 1 ? wk : wsel == 2 ? wv : wo;
    d = ws_base + (1L << 22) + ((long)wsel << 20);
  }
  float4 f = *reinterpret_cast<const float4*>(s + off);
  u16x4 o;
  o[0] = f2bf(f.x); o[1] = f2bf(f.y); o[2] = f2bf(f.z); o[3] = f2bf(f.w);
  *reinterpret_cast<u16x4*>(d + off) = o;
}

// ---------------- GEMM: C = A[M,1024] * B[N,1024]^T + bias ----------------
// MODE 0: fused QKV (A = x_bf16). grid.x = 24: nb>>3 selects Q/K/V. Q,K stored [B,H,S,64]; V stored [B,H,64,S].
// MODE 1: output projection (A = ctx_bf16), f32 flat output.
template<int MODE>
__global__ __launch_bounds__(256, 2)
void gemm_bt_kernel(const unsigned short* __restrict__ A,
                    const unsigned short* __restrict__ B0,
                    const unsigned short* __restrict__ B1,
                    const unsigned short* __restrict__ B2,
                    const float* __restrict__ bias0,
                    const float* __restrict__ bias1,
                    const float* __restrict__ bias2,
                    unsigned short* __restrict__ q_out,
                    unsigned short* __restrict__ k_out,
                    unsigned short* __restrict__ vt_out,
                    float* __restrict__ f_out)
{
  __shared__ unsigned short As[128 * 64];
  __shared__ unsigned short Bs[128 * 64];
  const int tid = threadIdx.x;
  const int lane = tid & 63;
  const int w = tid >> 6;
  const int wr = w >> 1, wc = w & 1;
  const int mBase = blockIdx.y * 128;
  int nb = blockIdx.x;
  const unsigned short* Bmat; const float* bias; int mat;
  if constexpr (MODE == 0) {
    mat = nb >> 3;
    nb &= 7;
    Bmat = mat == 0 ? B0 : (mat == 1 ? B1 : B2);
    bias = mat == 0 ? bias0 : (mat == 1 ? bias1 : bias2);
  } else { mat = 0; Bmat = B0; bias = bias0; }
  const int nBase = nb * 128;

  f32x4 acc[4][4] = {};
  const int srow = lane >> 3;                 // row within 8-row chunk
  const int ksrc = ((lane & 7) ^ srow) * 8;   // pre-swizzled source k-offset (elements)
  const unsigned short* ArowBase = A    + (size_t)(mBase + w * 32 + srow) * DM + ksrc;
  const unsigned short* BrowBase = Bmat + (size_t)(nBase + w * 32 + srow) * DM + ksrc;

  for (int kt = 0; kt < 16; ++kt) {
    #pragma unroll
    for (int i = 0; i < 4; ++i) {
      load_lds16(ArowBase + (size_t)(i * 8) * DM + kt * 64, &As[(w * 4 + i) * 512]);
      load_lds16(BrowBase + (size_t)(i * 8) * DM + kt * 64, &Bs[(w * 4 + i) * 512]);
    }
    __syncthreads();
    #pragma unroll
    for (int kk = 0; kk < 2; ++kk) {
      bf16x8 af[4], bfr[4];
      const int cb = kk * 64 + ((lane >> 4) << 4);
      #pragma unroll
      for (int m = 0; m < 4; ++m)
        af[m] = lds_swz_read(As, wr * 64 + m * 16 + (lane & 15), cb);
      #pragma unroll
      for (int n = 0; n < 4; ++n)
        bfr[n] = lds_swz_read(Bs, wc * 64 + n * 16 + (lane & 15), cb);
      #pragma unroll
      for (int m = 0; m < 4; ++m)
        #pragma unroll
        for (int n = 0; n < 4; ++n)
          acc[m][n] = mfma16(af[m], bfr[n], acc[m][n]);
    }
    __syncthreads();
  }

  // epilogue: bias + store
  #pragma unroll
  for (int m = 0; m < 4; ++m) {
    #pragma unroll
    for (int n = 0; n < 4; ++n) {
      const int col = nBase + wc * 64 + n * 16 + (lane & 15);
      const float bv = bias[col];
      const int row0 = mBase + wr * 64 + m * 16 + ((lane >> 4) << 2);
      if constexpr (MODE == 1) {
        #pragma unroll
        for (int j = 0; j < 4; ++j)
          f_out[(size_t)(row0 + j) * DM + col] = acc[m][n][j] + bv;
      } else {
        const int h = col >> 6, d = col & 63;
        if (mat < 2) {
          unsigned short* dst = (mat == 0) ? q_out : k_out;
          #pragma unroll
          for (int j = 0; j < 4; ++j) {
            const int row = row0 + j;
            const int b = row >> 11, s = row & 2047;
            dst[(((size_t)b * NH + h) * S_LEN + s) * HD + d] = f2bf(acc[m][n][j] + bv);
          }
        } else {
          const int b = row0 >> 11, s = row0 & 2047;
          u16x4 pk;
          #pragma unroll
          for (int j = 0; j < 4; ++j) pk[j] = f2bf(acc[m][n][j] + bv);
          *reinterpret_cast<u16x4*>(&vt_out[(((size_t)b * NH + h) * HD + d) * S_LEN + s]) = pk;
        }
      }
    }
  }
}

// ---------------- flash attention: counted-vmcnt pipeline (T3/T4) ----------------
// Round-5 structure (LDS K/V dbuf + per-wave P + reg bias prefetch) but the sync is
// raw s_barrier + counted s_waitcnt vmcnt(N) -- NEVER vmcnt(0) in steady state -- so
// prefetch loads stay in flight across barriers (__syncthreads drained them: the
// round-5 limiter). Bias/mask raw loads run 2 tiles ahead in two named reg sets;
// K/V staged 1 tile ahead (L2-resident, 1 compute phase of cover suffices).
// Per-wave per-tile VMEM: V(t+1) 2 + K(t+1) 2 + raw(t+2) 8, so end-of-tile
// s_waitcnt vmcnt(8) leaves exactly raw(t+2) in flight (FIFO).

#define WAITV8 do { asm volatile("s_waitcnt vmcnt(8)" ::: "memory"); } while (0)
#define WAITV0 do { asm volatile("s_waitcnt vmcnt(0)" ::: "memory"); } while (0)
#define SB0    __builtin_amdgcn_sched_barrier(0)
#define BAR    __builtin_amdgcn_s_barrier()

#define LOAD_RAW_A(kvB) do {                                                  \
    rbA0 = *reinterpret_cast<const f32x4*>(bp + (kvB) + g * 4);               \
    rmA0 = *reinterpret_cast<const f32x4*>(mp + (kvB) + g * 4);               \
    rbA1 = *reinterpret_cast<const f32x4*>(bp + (kvB) + 16 + g * 4);          \
    rmA1 = *reinterpret_cast<const f32x4*>(mp + (kvB) + 16 + g * 4);          \
    rbA2 = *reinterpret_cast<const f32x4*>(bp + (kvB) + 32 + g * 4);          \
    rmA2 = *reinterpret_cast<const f32x4*>(mp + (kvB) + 32 + g * 4);          \
    rbA3 = *reinterpret_cast<const f32x4*>(bp + (kvB) + 48 + g * 4);          \
    rmA3 = *reinterpret_cast<const f32x4*>(mp + (kvB) + 48 + g * 4);          \
  } while (0)

#define LOAD_RAW_B(kvB) do {                                                  \
    rbB0 = *reinterpret_cast<const f32x4*>(bp + (kvB) + g * 4);               \
    rmB0 = *reinterpret_cast<const f32x4*>(mp + (kvB) + g * 4);               \
    rbB1 = *reinterpret_cast<const f32x4*>(bp + (kvB) + 16 + g * 4);          \
    rmB1 = *reinterpret_cast<const f32x4*>(mp + (kvB) + 16 + g * 4);          \
    rbB2 = *reinterpret_cast<const f32x4*>(bp + (kvB) + 32 + g * 4);          \
    rmB2 = *reinterpret_cast<const f32x4*>(mp + (kvB) + 32 + g * 4);          \
    rbB3 = *reinterpret_cast<const f32x4*>(bp + (kvB) + 48 + g * 4);          \
    rmB3 = *reinterpret_cast<const f32x4*>(mp + (kvB) + 48 + g * 4);          \
  } while (0)

#define COMBINE_A do {                                                        \
    bm0 = (rbA0 + rmA0) * L2E; bm1 = (rbA1 + rmA1) * L2E;                     \
    bm2 = (rbA2 + rmA2) * L2E; bm3 = (rbA3 + rmA3) * L2E;                     \
  } while (0)

#define COMBINE_B do {                                                        \
    bm0 = (rbB0 + rmB0) * L2E; bm1 = (rbB1 + rmB1) * L2E;                     \
    bm2 = (rbB2 + rmB2) * L2E; bm3 = (rbB3 + rmB3) * L2E;                     \
  } while (0)

#define STAGE_K(kvB, buf) do {                                                               \
    load_lds16(Kp + (size_t)((kvB) + w * 16 + srow) * HD + ksrc,     &Ks[buf][(w * 2) * 512]);     \
    load_lds16(Kp + (size_t)((kvB) + w * 16 + 8 + srow) * HD + ksrc, &Ks[buf][(w * 2 + 1) * 512]); \
  } while (0)

#define STAGE_V(kvB, buf) do {                                                               \
    load_lds16(Vp + (size_t)(w * 16 + srow) * S_LEN + (kvB) + ksrc,     &Vs[buf][(w * 2) * 512]);     \
    load_lds16(Vp + (size_t)(w * 16 + 8 + srow) * S_LEN + (kvB) + ksrc, &Vs[buf][(w * 2 + 1) * 512]); \
  } while (0)

#define BIAS_COL(SCN, BMN) do {                                               \
    SCN[0] = SCN[0] * SC + BMN[0];                                            \
    SCN[1] = SCN[1] * SC + BMN[1];                                            \
    SCN[2] = SCN[2] * SC + BMN[2];                                            \
    SCN[3] = SCN[3] * SC + BMN[3];                                            \
    mt_ = fmaxf(mt_, fmaxf(fmaxf(SCN[0], SCN[1]), fmaxf(SCN[2], SCN[3])));    \
  } while (0)

#define EXP_COL(SCN) do {                                                     \
    SCN[0] = EXP2F(SCN[0] - mn_); SCN[1] = EXP2F(SCN[1] - mn_);               \
    SCN[2] = EXP2F(SCN[2] - mn_); SCN[3] = EXP2F(SCN[3] - mn_);               \
  } while (0)

#define PWR_COL(NN, SCN) do {                                                 \
    u16x4 pk_;                                                                \
    pk_[0] = f2bf(SCN[0]); pk_[1] = f2bf(SCN[1]);                             \
    pk_[2] = f2bf(SCN[2]); pk_[3] = f2bf(SCN[3]);                             \
    const int colb_ = ((NN) * 16 + 4 * g) * 2;                                \
    *reinterpret_cast<u16x4*>(                                                \
        reinterpret_cast<char*>(Pw_) + (q << 7) + (colb_ ^ ((q & 7) << 4))) = pk_; \
  } while (0)

#define COMPUTE_TILE(KSB, VSB) do {                                           \
    const unsigned short* KSB_ = (KSB);                                       \
    const unsigned short* VSB_ = (VSB);                                       \
    f32x4 sc0_, sc1_, sc2_, sc3_;                                             \
    { bf16x8 a_ = lds_swz_read(KSB_, 0 * 16 + q, cbq);                        \
      bf16x8 b_ = lds_swz_read(KSB_, 0 * 16 + q, 64 + cbq);                   \
      f32x4 z_ = {}; z_ = mfma16(a_, qf0, z_); sc0_ = mfma16(b_, qf1, z_); }  \
    { bf16x8 a_ = lds_swz_read(KSB_, 1 * 16 + q, cbq);                        \
      bf16x8 b_ = lds_swz_read(KSB_, 1 * 16 + q, 64 + cbq);                   \
      f32x4 z_ = {}; z_ = mfma16(a_, qf0, z_); sc1_ = mfma16(b_, qf1, z_); }  \
    { bf16x8 a_ = lds_swz_read(KSB_, 2 * 16 + q, cbq);                        \
      bf16x8 b_ = lds_swz_read(KSB_, 2 * 16 + q, 64 + cbq);                   \
      f32x4 z_ = {}; z_ = mfma16(a_, qf0, z_); sc2_ = mfma16(b_, qf1, z_); }  \
    { bf16x8 a_ = lds_swz_read(KSB_, 3 * 16 + q, cbq);                        \
      bf16x8 b_ = lds_swz_read(KSB_, 3 * 16 + q, 64 + cbq);                   \
      f32x4 z_ = {}; z_ = mfma16(a_, qf0, z_); sc3_ = mfma16(b_, qf1, z_); }  \
    float mt_ = -3.0e38f;                                                     \
    BIAS_COL(sc0_, bm0); BIAS_COL(sc1_, bm1);                                 \
    BIAS_COL(sc2_, bm2); BIAS_COL(sc3_, bm3);                                 \
    mt_ = fmaxf(mt_, __shfl_xor(mt_, 16));                                    \
    mt_ = fmaxf(mt_, __shfl_xor(mt_, 32));                                    \
    const float mn_ = fmaxf(m_run, mt_);                                      \
    const float corr_ = EXP2F(m_run - mn_);                                   \
    m_run = mn_;                                                              \
    EXP_COL(sc0_); EXP_COL(sc1_); EXP_COL(sc2_); EXP_COL(sc3_);               \
    f32x4 ls4_ = sc0_ + sc1_ + sc2_ + sc3_;                                   \
    float ls_ = ls4_[0] + ls4_[1] + ls4_[2] + ls4_[3];                        \
    ls_ += __shfl_xor(ls_, 16);                                               \
    ls_ += __shfl_xor(ls_, 32);                                               \
    l_run = l_run * corr_ + ls_;                                              \
    acc0_ *= corr_; acc1_ *= corr_; acc2_ *= corr_; acc3_ *= corr_;           \
    PWR_COL(0, sc0_); PWR_COL(1, sc1_); PWR_COL(2, sc2_); PWR_COL(3, sc3_);   \
    bf16x8 pf0_ = lds_swz_read(Pw_, q, cbq);                                  \
    bf16x8 pf1_ = lds_swz_read(Pw_, q, 64 + cbq);                             \
    { bf16x8 a_ = lds_swz_read(VSB_, 0 * 16 + q, cbq);                        \
      bf16x8 b_ = lds_swz_read(VSB_, 0 * 16 + q, 64 + cbq);                   \
      acc0_ = mfma16(a_, pf0_, acc0_); acc0_ = mfma16(b_, pf1_, acc0_); }     \
    { bf16x8 a_ = lds_swz_read(VSB_, 1 * 16 + q, cbq);                        \
      bf16x8 b_ = lds_swz_read(VSB_, 1 * 16 + q, 64 + cbq);                   \
      acc1_ = mfma16(a_, pf0_, acc1_); acc1_ = mfma16(b_, pf1_, acc1_); }     \
    { bf16x8 a_ = lds_swz_read(VSB_, 2 * 16 + q, cbq);                        \
      bf16x8 b_ = lds_swz_read(VSB_, 2 * 16 + q, 64 + cbq);                   \
      acc2_ = mfma16(a_, pf0_, acc2_); acc2_ = mfma16(b_, pf1_, acc2_); }     \
    { bf16x8 a_ = lds_swz_read(VSB_, 3 * 16 + q, cbq);                        \
      bf16x8 b_ = lds_swz_read(VSB_, 3 * 16 + q, 64 + cbq);                   \
      acc3_ = mfma16(a_, pf0_, acc3_); acc3_ = mfma16(b_, pf1_, acc3_); }     \
  } while (0)

__global__ __launch_bounds__(256) __attribute__((amdgpu_waves_per_eu(3, 4)))
void attn_kernel(const unsigned short* __restrict__ Q,
                 const unsigned short* __restrict__ Kmat,
                 const unsigned short* __restrict__ Vt,
                 const float* __restrict__ rel_bias,
                 const float* __restrict__ mask,
                 unsigned short* __restrict__ ctx)
{
  __shared__ unsigned short Ks[2][64 * 64];
  __shared__ unsigned short Vs[2][64 * 64];
  __shared__ unsigned short Ps[4][16 * 64];

  // XCD-chunked bijective remap: 1024 = 8 XCDs x 128; b is fastest in logical id
  const int logical = (blockIdx.x & 7) * 128 + (blockIdx.x >> 3);
  const int b  = logical & 1;
  const int qt = (logical >> 1) & 31;
  const int h  = logical >> 6;

  const int lane = threadIdx.x & 63, w = threadIdx.x >> 6;
  const int q = lane & 15, g = lane >> 4;
  const size_t bh = (size_t)b * NH + h;
  const int qRow = qt * 64 + w * 16;
  const unsigned short* Qp = Q + (bh * S_LEN + qRow) * HD;
  bf16x8 qf0 = *reinterpret_cast<const bf16x8*>(Qp + (size_t)q * HD + g * 8);
  bf16x8 qf1 = *reinterpret_cast<const bf16x8*>(Qp + (size_t)q * HD + 32 + g * 8);

  const unsigned short* Kp = Kmat + bh * (size_t)S_LEN * HD;
  const unsigned short* Vp = Vt + bh * (size_t)HD * S_LEN;
  const float* bp = rel_bias + (size_t)h * S_LEN * S_LEN + (size_t)(qRow + q) * S_LEN;
  const float* mp = mask + (size_t)(qRow + q) * S_LEN;

  float m_run = -3.0e38f, l_run = 0.f;
  f32x4 acc0_ = {}, acc1_ = {}, acc2_ = {}, acc3_ = {};
  f32x4 rbA0, rbA1, rbA2, rbA3, rmA0, rmA1, rmA2, rmA3;
  f32x4 rbB0, rbB1, rbB2, rbB3, rmB0, rmB1, rmB2, rmB3;
  f32x4 bm0, bm1, bm2, bm3;

  const float SC  = 0.125f * 1.44269504089f;  // head scale * log2(e)
  const float L2E = 1.44269504089f;

  const int srow = lane >> 3;
  const int ksrc = ((lane & 7) ^ srow) * 8;   // pre-swizzled global k-offset
  const int cbq = g << 4;
  unsigned short* Pw_ = Ps[w];

  // prologue: prime the FIFO to the steady-state invariant
  // issue order: V0(2) K0(2) rawA(0)(8) rawB(1)(8) -> wait vmcnt(8) leaves rawB in flight
  STAGE_V(0, 0);
  STAGE_K(0, 0);
  LOAD_RAW_A(0);
  LOAD_RAW_B(64);
  SB0;
  WAITV8; SB0; BAR;

  for (int i = 0; i < 15; ++i) {
    const int t0 = 2 * i;
    // ---- tile t0 (even): Ks[0], Vs[0], set A ----
    COMBINE_A;
    STAGE_V((t0 + 1) * 64, 1);
    STAGE_K((t0 + 1) * 64, 1);
    LOAD_RAW_A((t0 + 2) * 64);
    SB0;
    COMPUTE_TILE(Ks[0], Vs[0]);
    WAITV8; SB0; BAR;
    // ---- tile t0+1 (odd): Ks[1], Vs[1], set B ----
    COMBINE_B;
    STAGE_V((t0 + 2) * 64, 0);
    STAGE_K((t0 + 2) * 64, 0);
    LOAD_RAW_B((t0 + 3) * 64);
    SB0;
    COMPUTE_TILE(Ks[1], Vs[1]);
    WAITV8; SB0; BAR;
  }

  // ---- tile 30: stage 31, no more raw loads ----
  COMBINE_A;
  STAGE_V(31 * 64, 1);
  STAGE_K(31 * 64, 1);
  SB0;
  COMPUTE_TILE(Ks[0], Vs[0]);
  WAITV0; SB0; BAR;
  // ---- tile 31 ----
  COMBINE_B;
  SB0;
  COMPUTE_TILE(Ks[1], Vs[1]);

  // epilogue: normalize, redistribute through per-wave LDS, coalesced 16B stores
  const float inv = 1.0f / l_run;
  acc0_ *= inv; acc1_ *= inv; acc2_ *= inv; acc3_ *= inv;
  PWR_COL(0, acc0_); PWR_COL(1, acc1_); PWR_COL(2, acc2_); PWR_COL(3, acc3_);
  bf16x8 c0 = lds_swz_read(Pw_, q, g << 4);
  bf16x8 c1 = lds_swz_read(Pw_, q, 64 + (g << 4));
  unsigned short* cp = ctx + ((size_t)b * S_LEN + qRow + q) * DM + h * HD;
  *reinterpret_cast<bf16x8*>(cp + 8 * g) = c0;
  *reinterpret_cast<bf16x8*>(cp + 32 + 8 * g) = c1;
}

extern "C" void kernel_launch(void* const* d_in, const int* in_sizes, int n_in,
                              void* d_out, int out_size, void* d_ws, size_t ws_size,
                              hipStream_t stream) {
  (void)in_sizes; (void)n_in; (void)out_size; (void)ws_size;
  const float* x  = (const float*)d_in[0];
  const float* rb = (const float*)d_in[1];
  const float* mk = (const float*)d_in[2];
  const float* Wq = (const float*)d_in[3];
  const float* bq = (const float*)d_in[4];
  const float* Wk = (const float*)d_in[5];
  const float* bk = (const float*)d_in[6];
  const float* Wv = (const float*)d_in[7];
  const float* bv = (const float*)d_in[8];
  const float* Wo = (const float*)d_in[9];
  const float* bo = (const float*)d_in[10];
  float* out = (float*)d_out;

  unsigned short* ws  = (unsigned short*)d_ws;
  unsigned short* xb  = ws;                       // 4M elems
  unsigned short* wqb = ws + (1L << 22);          // 1M
  unsigned short* wkb = wqb + (1L << 20);
  unsigned short* wvb = wkb + (1L << 20);
  unsigned short* wob = wvb + (1L << 20);
  unsigned short* Qw  = wob + (1L << 20);         // 4M [B,H,S,64]
  unsigned short* Kw  = Qw + (1L << 22);          // 4M [B,H,S,64]
  unsigned short* Vtw = Kw + (1L << 22);          // 4M [B,H,64,S]
  unsigned short* ctx = Vtw + (1L << 22);         // 4M [B,S,DM]

  prep_kernel<<<8192, 256, 0, stream>>>(x, Wq, Wk, Wv, Wo, ws);
  gemm_bt_kernel<0><<<dim3(24, 32), 256, 0, stream>>>(
      xb, wqb, wkb, wvb, bq, bk, bv, Qw, Kw, Vtw, nullptr);
  attn_kernel<<<1024, 256, 0, stream>>>(Qw, Kw, Vtw, rb, mk, ctx);
  gemm_bt_kernel<1><<<dim3(8, 32), 256, 0, stream>>>(
      ctx, wob, nullptr, nullptr, bo, nullptr, nullptr, nullptr, nullptr, nullptr, out);
}

// Round 9
// 237.583 us; speedup vs baseline: 1.8171x; 1.0150x over previous
//
#include <hip/hip_runtime.h>
#include <hip/hip_bf16.h>
#include <stdint.h>

#define S_LEN 2048
#define DM 1024
#define NH 16
#define HD 64

typedef __bf16 bf16x8 __attribute__((ext_vector_type(8)));
typedef float f32x4 __attribute__((ext_vector_type(4)));
typedef unsigned short u16x4 __attribute__((ext_vector_type(4)));

#if __has_builtin(__builtin_amdgcn_exp2f)
#define EXP2F(x) __builtin_amdgcn_exp2f(x)
#else
#define EXP2F(x) exp2f(x)
#endif

__device__ __forceinline__ unsigned short f2bf(float f){
  union { float f; uint32_t u; } v; v.f = f;
  uint32_t r = v.u + 0x7fffu + ((v.u >> 16) & 1u);
  return (unsigned short)(r >> 16);
}

__device__ __forceinline__ void load_lds16(const void* g, void* l){
  __builtin_amdgcn_global_load_lds((const __attribute__((address_space(1))) void*)g,
                                   (__attribute__((address_space(3))) void*)l, 16, 0, 0);
}

__device__ __forceinline__ f32x4 mfma16(bf16x8 a, bf16x8 b, f32x4 c){
  return __builtin_amdgcn_mfma_f32_16x16x32_bf16(a, b, c, 0, 0, 0);
}

// rows are 64 bf16 = 128B; swizzle byte_off ^= ((row&7)<<4) to break the 128B-stride bank conflict
__device__ __forceinline__ bf16x8 lds_swz_read(const unsigned short* base, int row, int cb){
  int addr = (row << 7) + (cb ^ ((row & 7) << 4));
  return *reinterpret_cast<const bf16x8*>(reinterpret_cast<const char*>(base) + addr);
}

// ---------------- prep: f32 -> bf16 for x and the 4 weight matrices ----------------
__global__ void prep_kernel(const float* __restrict__ x,
                            const float* __restrict__ wq, const float* __restrict__ wk,
                            const float* __restrict__ wv, const float* __restrict__ wo,
                            unsigned short* __restrict__ ws_base){
  long idx = ((long)blockIdx.x * 256 + threadIdx.x) * 4;
  const float* s; unsigned short* d; long off;
  if (idx < (1L << 22)) { s = x; d = ws_base; off = idx; }
  else {
    long r = idx - (1L << 22);
    int wsel = (int)(r >> 20);
    off = r & ((1L << 20) - 1);
    s = wsel == 0 ? wq : wsel == 1 ? wk : wsel == 2 ? wv : wo;
    d = ws_base + (1L << 22) + ((long)wsel << 20);
  }
  float4 f = *reinterpret_cast<const float4*>(s + off);
  u16x4 o;
  o[0] = f2bf(f.x); o[1] = f2bf(f.y); o[2] = f2bf(f.z); o[3] = f2bf(f.w);
  *reinterpret_cast<u16x4*>(d + off) = o;
}

// ---------------- GEMM: C = A[M,1024] * B[N,1024]^T + bias ----------------
template<int MODE>
__global__ __launch_bounds__(256, 2)
void gemm_bt_kernel(const unsigned short* __restrict__ A,
                    const unsigned short* __restrict__ B0,
                    const unsigned short* __restrict__ B1,
                    const unsigned short* __restrict__ B2,
                    const float* __restrict__ bias0,
                    const float* __restrict__ bias1,
                    const float* __restrict__ bias2,
                    unsigned short* __restrict__ q_out,
                    unsigned short* __restrict__ k_out,
                    unsigned short* __restrict__ vt_out,
                    float* __restrict__ f_out)
{
  __shared__ unsigned short As[128 * 64];
  __shared__ unsigned short Bs[128 * 64];
  const int tid = threadIdx.x;
  const int lane = tid & 63;
  const int w = tid >> 6;
  const int wr = w >> 1, wc = w & 1;
  const int mBase = blockIdx.y * 128;
  int nb = blockIdx.x;
  const unsigned short* Bmat; const float* bias; int mat;
  if constexpr (MODE == 0) {
    mat = nb >> 3;
    nb &= 7;
    Bmat = mat == 0 ? B0 : (mat == 1 ? B1 : B2);
    bias = mat == 0 ? bias0 : (mat == 1 ? bias1 : bias2);
  } else { mat = 0; Bmat = B0; bias = bias0; }
  const int nBase = nb * 128;

  f32x4 acc[4][4] = {};
  const int srow = lane >> 3;
  const int ksrc = ((lane & 7) ^ srow) * 8;
  const unsigned short* ArowBase = A    + (size_t)(mBase + w * 32 + srow) * DM + ksrc;
  const unsigned short* BrowBase = Bmat + (size_t)(nBase + w * 32 + srow) * DM + ksrc;

  for (int kt = 0; kt < 16; ++kt) {
    #pragma unroll
    for (int i = 0; i < 4; ++i) {
      load_lds16(ArowBase + (size_t)(i * 8) * DM + kt * 64, &As[(w * 4 + i) * 512]);
      load_lds16(BrowBase + (size_t)(i * 8) * DM + kt * 64, &Bs[(w * 4 + i) * 512]);
    }
    __syncthreads();
    #pragma unroll
    for (int kk = 0; kk < 2; ++kk) {
      bf16x8 af[4], bfr[4];
      const int cb = kk * 64 + ((lane >> 4) << 4);
      #pragma unroll
      for (int m = 0; m < 4; ++m)
        af[m] = lds_swz_read(As, wr * 64 + m * 16 + (lane & 15), cb);
      #pragma unroll
      for (int n = 0; n < 4; ++n)
        bfr[n] = lds_swz_read(Bs, wc * 64 + n * 16 + (lane & 15), cb);
      #pragma unroll
      for (int m = 0; m < 4; ++m)
        #pragma unroll
        for (int n = 0; n < 4; ++n)
          acc[m][n] = mfma16(af[m], bfr[n], acc[m][n]);
    }
    __syncthreads();
  }

  #pragma unroll
  for (int m = 0; m < 4; ++m) {
    #pragma unroll
    for (int n = 0; n < 4; ++n) {
      const int col = nBase + wc * 64 + n * 16 + (lane & 15);
      const float bv = bias[col];
      const int row0 = mBase + wr * 64 + m * 16 + ((lane >> 4) << 2);
      if constexpr (MODE == 1) {
        #pragma unroll
        for (int j = 0; j < 4; ++j)
          f_out[(size_t)(row0 + j) * DM + col] = acc[m][n][j] + bv;
      } else {
        const int h = col >> 6, d = col & 63;
        if (mat < 2) {
          unsigned short* dst = (mat == 0) ? q_out : k_out;
          #pragma unroll
          for (int j = 0; j < 4; ++j) {
            const int row = row0 + j;
            const int b = row >> 11, s = row & 2047;
            dst[(((size_t)b * NH + h) * S_LEN + s) * HD + d] = f2bf(acc[m][n][j] + bv);
          }
        } else {
          const int b = row0 >> 11, s = row0 & 2047;
          u16x4 pk;
          #pragma unroll
          for (int j = 0; j < 4; ++j) pk[j] = f2bf(acc[m][n][j] + bv);
          *reinterpret_cast<u16x4*>(&vt_out[(((size_t)b * NH + h) * HD + d) * S_LEN + s]) = pk;
        }
      }
    }
  }
}

// ---------------- flash attention: TWO-TILE pipelined (T15) + counted vmcnt, RACE-FIXED ----------------
// r8 raced: raw loads were issued FIRST each phase, so vmcnt(8) retired them and left the
// K/V global_load_lds writes in flight across the barrier -- the next phase ds_read those
// buffers stale. Fix: issue STAGE_K/STAGE_V FIRST and LOAD_RAW LAST (fenced by
// sched_barrier), so vmcnt(8) retires exactly the 4 stage ops and leaves the 8 raw
// register-dest loads in flight (their consumer COMBINE gets a compiler-inserted wait).
// Phase t: COMBINE(raw t) | stage K(t+2)->Ks[t&1], V(t+1)->Vs[(t+1)&1], raw(t+1) |
//          QK(t+1) from Ks[(t+1)&1] (MFMA pipe) | softmax+PV(t) (VALU) | vmcnt(8); bar.

#define WAITV8 do { asm volatile("s_waitcnt vmcnt(8)" ::: "memory"); } while (0)
#define WAITV0 do { asm volatile("s_waitcnt vmcnt(0)" ::: "memory"); } while (0)
#define SB0    __builtin_amdgcn_sched_barrier(0)
#define BAR    __builtin_amdgcn_s_barrier()

#define LOAD_RAW(kvB) do {                                                    \
    rb0 = *reinterpret_cast<const f32x4*>(bp + (kvB) + g * 4);                \
    rm0 = *reinterpret_cast<const f32x4*>(mp + (kvB) + g * 4);                \
    rb1 = *reinterpret_cast<const f32x4*>(bp + (kvB) + 16 + g * 4);           \
    rm1 = *reinterpret_cast<const f32x4*>(mp + (kvB) + 16 + g * 4);           \
    rb2 = *reinterpret_cast<const f32x4*>(bp + (kvB) + 32 + g * 4);           \
    rm2 = *reinterpret_cast<const f32x4*>(mp + (kvB) + 32 + g * 4);           \
    rb3 = *reinterpret_cast<const f32x4*>(bp + (kvB) + 48 + g * 4);           \
    rm3 = *reinterpret_cast<const f32x4*>(mp + (kvB) + 48 + g * 4);           \
  } while (0)

#define COMBINE do {                                                          \
    bm0 = (rb0 + rm0) * L2E; bm1 = (rb1 + rm1) * L2E;                         \
    bm2 = (rb2 + rm2) * L2E; bm3 = (rb3 + rm3) * L2E;                         \
  } while (0)

#define STAGE_K(kvB, buf) do {                                                               \
    load_lds16(Kp + (size_t)((kvB) + w * 16 + srow) * HD + ksrc,     &Ks[buf][(w * 2) * 512]);     \
    load_lds16(Kp + (size_t)((kvB) + w * 16 + 8 + srow) * HD + ksrc, &Ks[buf][(w * 2 + 1) * 512]); \
  } while (0)

#define STAGE_V(kvB, buf) do {                                                               \
    load_lds16(Vp + (size_t)(w * 16 + srow) * S_LEN + (kvB) + ksrc,     &Vs[buf][(w * 2) * 512]);     \
    load_lds16(Vp + (size_t)(w * 16 + 8 + srow) * S_LEN + (kvB) + ksrc, &Vs[buf][(w * 2 + 1) * 512]); \
  } while (0)

// QK for one tile into the given named sc regs (MFMA pipe; results used next phase)
#define QK_TILE(S0, S1, S2, S3, KSB) do {                                     \
    const unsigned short* KQ_ = (KSB);                                        \
    { bf16x8 a_ = lds_swz_read(KQ_, 0 * 16 + q, cbq);                         \
      bf16x8 b_ = lds_swz_read(KQ_, 0 * 16 + q, 64 + cbq);                    \
      f32x4 z_ = {}; z_ = mfma16(a_, qf0, z_); S0 = mfma16(b_, qf1, z_); }    \
    { bf16x8 a_ = lds_swz_read(KQ_, 1 * 16 + q, cbq);                         \
      bf16x8 b_ = lds_swz_read(KQ_, 1 * 16 + q, 64 + cbq);                    \
      f32x4 z_ = {}; z_ = mfma16(a_, qf0, z_); S1 = mfma16(b_, qf1, z_); }    \
    { bf16x8 a_ = lds_swz_read(KQ_, 2 * 16 + q, cbq);                         \
      bf16x8 b_ = lds_swz_read(KQ_, 2 * 16 + q, 64 + cbq);                    \
      f32x4 z_ = {}; z_ = mfma16(a_, qf0, z_); S2 = mfma16(b_, qf1, z_); }    \
    { bf16x8 a_ = lds_swz_read(KQ_, 3 * 16 + q, cbq);                         \
      bf16x8 b_ = lds_swz_read(KQ_, 3 * 16 + q, 64 + cbq);                    \
      f32x4 z_ = {}; z_ = mfma16(a_, qf0, z_); S3 = mfma16(b_, qf1, z_); }    \
  } while (0)

#define BIAS_COL(SCN, BMN) do {                                               \
    SCN[0] = SCN[0] * SC + BMN[0];                                            \
    SCN[1] = SCN[1] * SC + BMN[1];                                            \
    SCN[2] = SCN[2] * SC + BMN[2];                                            \
    SCN[3] = SCN[3] * SC + BMN[3];                                            \
    mt_ = fmaxf(mt_, fmaxf(fmaxf(SCN[0], SCN[1]), fmaxf(SCN[2], SCN[3])));    \
  } while (0)

#define EXP_COL(SCN) do {                                                     \
    SCN[0] = EXP2F(SCN[0] - mn_); SCN[1] = EXP2F(SCN[1] - mn_);               \
    SCN[2] = EXP2F(SCN[2] - mn_); SCN[3] = EXP2F(SCN[3] - mn_);               \
  } while (0)

#define PWR_COL(NN, SCN) do {                                                 \
    u16x4 pk_;                                                                \
    pk_[0] = f2bf(SCN[0]); pk_[1] = f2bf(SCN[1]);                             \
    pk_[2] = f2bf(SCN[2]); pk_[3] = f2bf(SCN[3]);                             \
    const int colb_ = ((NN) * 16 + 4 * g) * 2;                                \
    *reinterpret_cast<u16x4*>(                                                \
        reinterpret_cast<char*>(Pw_) + (q << 7) + (colb_ ^ ((q & 7) << 4))) = pk_; \
  } while (0)

// softmax + P roundtrip + PV for the tile whose scores are in S0..S3
#define SOFTMAX_PV(S0, S1, S2, S3, VSB) do {                                  \
    const unsigned short* VQ_ = (VSB);                                        \
    float mt_ = -3.0e38f;                                                     \
    BIAS_COL(S0, bm0); BIAS_COL(S1, bm1);                                     \
    BIAS_COL(S2, bm2); BIAS_COL(S3, bm3);                                     \
    mt_ = fmaxf(mt_, __shfl_xor(mt_, 16));                                    \
    mt_ = fmaxf(mt_, __shfl_xor(mt_, 32));                                    \
    const float mn_ = fmaxf(m_run, mt_);                                      \
    const float corr_ = EXP2F(m_run - mn_);                                   \
    m_run = mn_;                                                              \
    EXP_COL(S0); EXP_COL(S1); EXP_COL(S2); EXP_COL(S3);                       \
    f32x4 ls4_ = S0 + S1 + S2 + S3;                                           \
    float ls_ = ls4_[0] + ls4_[1] + ls4_[2] + ls4_[3];                        \
    ls_ += __shfl_xor(ls_, 16);                                               \
    ls_ += __shfl_xor(ls_, 32);                                               \
    l_run = l_run * corr_ + ls_;                                              \
    acc0_ *= corr_; acc1_ *= corr_; acc2_ *= corr_; acc3_ *= corr_;           \
    PWR_COL(0, S0); PWR_COL(1, S1); PWR_COL(2, S2); PWR_COL(3, S3);           \
    bf16x8 pf0_ = lds_swz_read(Pw_, q, cbq);                                  \
    bf16x8 pf1_ = lds_swz_read(Pw_, q, 64 + cbq);                             \
    { bf16x8 a_ = lds_swz_read(VQ_, 0 * 16 + q, cbq);                         \
      bf16x8 b_ = lds_swz_read(VQ_, 0 * 16 + q, 64 + cbq);                    \
      acc0_ = mfma16(a_, pf0_, acc0_); acc0_ = mfma16(b_, pf1_, acc0_); }     \
    { bf16x8 a_ = lds_swz_read(VQ_, 1 * 16 + q, cbq);                         \
      bf16x8 b_ = lds_swz_read(VQ_, 1 * 16 + q, 64 + cbq);                    \
      acc1_ = mfma16(a_, pf0_, acc1_); acc1_ = mfma16(b_, pf1_, acc1_); }     \
    { bf16x8 a_ = lds_swz_read(VQ_, 2 * 16 + q, cbq);                         \
      bf16x8 b_ = lds_swz_read(VQ_, 2 * 16 + q, 64 + cbq);                    \
      acc2_ = mfma16(a_, pf0_, acc2_); acc2_ = mfma16(b_, pf1_, acc2_); }     \
    { bf16x8 a_ = lds_swz_read(VQ_, 3 * 16 + q, cbq);                         \
      bf16x8 b_ = lds_swz_read(VQ_, 3 * 16 + q, 64 + cbq);                    \
      acc3_ = mfma16(a_, pf0_, acc3_); acc3_ = mfma16(b_, pf1_, acc3_); }     \
  } while (0)

// one pipeline phase: SCC = current tile's scores; SCN = next tile's score regs
#define PHASE(t, SCC0, SCC1, SCC2, SCC3, SCN0, SCN1, SCN2, SCN3, DO_K, DO_RAW) do { \
    COMBINE;                                                                  \
    if (DO_K) STAGE_K(((t) + 2) * 64, (t) & 1);                               \
    STAGE_V(((t) + 1) * 64, ((t) + 1) & 1);                                   \
    SB0;                                                                      \
    if (DO_RAW) LOAD_RAW(((t) + 1) * 64);                                     \
    SB0;                                                                      \
    QK_TILE(SCN0, SCN1, SCN2, SCN3, Ks[((t) + 1) & 1]);                       \
    SOFTMAX_PV(SCC0, SCC1, SCC2, SCC3, Vs[(t) & 1]);                          \
    WAITV8; SB0; BAR;                                                         \
  } while (0)

__global__ __launch_bounds__(256) __attribute__((amdgpu_waves_per_eu(3, 4)))
void attn_kernel(const unsigned short* __restrict__ Q,
                 const unsigned short* __restrict__ Kmat,
                 const unsigned short* __restrict__ Vt,
                 const float* __restrict__ rel_bias,
                 const float* __restrict__ mask,
                 unsigned short* __restrict__ ctx)
{
  __shared__ unsigned short Ks[2][64 * 64];
  __shared__ unsigned short Vs[2][64 * 64];
  __shared__ unsigned short Ps[4][16 * 64];

  // XCD-chunked bijective remap: 1024 = 8 XCDs x 128; b is fastest in logical id
  const int logical = (blockIdx.x & 7) * 128 + (blockIdx.x >> 3);
  const int b  = logical & 1;
  const int qt = (logical >> 1) & 31;
  const int h  = logical >> 6;

  const int lane = threadIdx.x & 63, w = threadIdx.x >> 6;
  const int q = lane & 15, g = lane >> 4;
  const size_t bh = (size_t)b * NH + h;
  const int qRow = qt * 64 + w * 16;
  const unsigned short* Qp = Q + (bh * S_LEN + qRow) * HD;
  bf16x8 qf0 = *reinterpret_cast<const bf16x8*>(Qp + (size_t)q * HD + g * 8);
  bf16x8 qf1 = *reinterpret_cast<const bf16x8*>(Qp + (size_t)q * HD + 32 + g * 8);

  const unsigned short* Kp = Kmat + bh * (size_t)S_LEN * HD;
  const unsigned short* Vp = Vt + bh * (size_t)HD * S_LEN;
  const float* bp = rel_bias + (size_t)h * S_LEN * S_LEN + (size_t)(qRow + q) * S_LEN;
  const float* mp = mask + (size_t)(qRow + q) * S_LEN;

  float m_run = -3.0e38f, l_run = 0.f;
  f32x4 acc0_ = {}, acc1_ = {}, acc2_ = {}, acc3_ = {};
  f32x4 rb0, rb1, rb2, rb3, rm0, rm1, rm2, rm3;
  f32x4 bm0, bm1, bm2, bm3;
  f32x4 scE0, scE1, scE2, scE3, scO0, scO1, scO2, scO3;

  const float SC  = 0.125f * 1.44269504089f;  // head scale * log2(e)
  const float L2E = 1.44269504089f;

  const int srow = lane >> 3;
  const int ksrc = ((lane & 7) ^ srow) * 8;   // pre-swizzled global k-offset
  const int cbq = g << 4;
  unsigned short* Pw_ = Ps[w];

  // prologue: stage V(0)->Vs[0], K(0)->Ks[0], K(1)->Ks[1]; drain; barrier;
  // raw(0) issued (8 in flight crossing the next barrier); QK(0) precomputed into E.
  STAGE_V(0, 0);
  STAGE_K(0, 0);
  STAGE_K(64, 1);
  SB0;
  WAITV0; SB0; BAR;
  LOAD_RAW(0);
  SB0;
  QK_TILE(scE0, scE1, scE2, scE3, Ks[0]);
  BAR;   // all waves' QK(0) reads retired before phase 0 overwrites Ks[0]

  for (int i = 0; i < 15; ++i) {
    const int t0 = 2 * i;
    PHASE(t0,     scE0, scE1, scE2, scE3, scO0, scO1, scO2, scO3, true, true);
    PHASE(t0 + 1, scO0, scO1, scO2, scO3, scE0, scE1, scE2, scE3, true, true);
  }
  // t=30: no K stage (t+2 OOB), raw(31) still loaded
  PHASE(30, scE0, scE1, scE2, scE3, scO0, scO1, scO2, scO3, false, true);
  // t=31: final tile -- COMBINE drains raw(31); no stages, no QK
  COMBINE;
  SOFTMAX_PV(scO0, scO1, scO2, scO3, Vs[1]);

  // epilogue: normalize, redistribute through per-wave LDS, coalesced 16B stores
  const float inv = 1.0f / l_run;
  acc0_ *= inv; acc1_ *= inv; acc2_ *= inv; acc3_ *= inv;
  PWR_COL(0, acc0_); PWR_COL(1, acc1_); PWR_COL(2, acc2_); PWR_COL(3, acc3_);
  bf16x8 c0 = lds_swz_read(Pw_, q, g << 4);
  bf16x8 c1 = lds_swz_read(Pw_, q, 64 + (g << 4));
  unsigned short* cp = ctx + ((size_t)b * S_LEN + qRow + q) * DM + h * HD;
  *reinterpret_cast<bf16x8*>(cp + 8 * g) = c0;
  *reinterpret_cast<bf16x8*>(cp + 32 + 8 * g) = c1;
}

extern "C" void kernel_launch(void* const* d_in, const int* in_sizes, int n_in,
                              void* d_out, int out_size, void* d_ws, size_t ws_size,
                              hipStream_t stream) {
  (void)in_sizes; (void)n_in; (void)out_size; (void)ws_size;
  const float* x  = (const float*)d_in[0];
  const float* rb = (const float*)d_in[1];
  const float* mk = (const float*)d_in[2];
  const float* Wq = (const float*)d_in[3];
  const float* bq = (const float*)d_in[4];
  const float* Wk = (const float*)d_in[5];
  const float* bk = (const float*)d_in[6];
  const float* Wv = (const float*)d_in[7];
  const float* bv = (const float*)d_in[8];
  const float* Wo = (const float*)d_in[9];
  const float* bo = (const float*)d_in[10];
  float* out = (float*)d_out;

  unsigned short* ws  = (unsigned short*)d_ws;
  unsigned short* xb  = ws;                       // 4M elems
  unsigned short* wqb = ws + (1L << 22);          // 1M
  unsigned short* wkb = wqb + (1L << 20);
  unsigned short* wvb = wkb + (1L << 20);
  unsigned short* wob = wvb + (1L << 20);
  unsigned short* Qw  = wob + (1L << 20);         // 4M [B,H,S,64]
  unsigned short* Kw  = Qw + (1L << 22);          // 4M [B,H,S,64]
  unsigned short* Vtw = Kw + (1L << 22);          // 4M [B,H,64,S]
  unsigned short* ctx = Vtw + (1L << 22);         // 4M [B,S,DM]

  prep_kernel<<<8192, 256, 0, stream>>>(x, Wq, Wk, Wv, Wo, ws);
  gemm_bt_kernel<0><<<dim3(24, 32), 256, 0, stream>>>(
      xb, wqb, wkb, wvb, bq, bk, bv, Qw, Kw, Vtw, nullptr);
  attn_kernel<<<1024, 256, 0, stream>>>(Qw, Kw, Vtw, rb, mk, ctx);
  gemm_bt_kernel<1><<<dim3(8, 32), 256, 0, stream>>>(
      ctx, wob, nullptr, nullptr, bo, nullptr, nullptr, nullptr, nullptr, nullptr, out);
}